// Round 5
// baseline (158.619 us; speedup 1.0000x reference)
//
#include <hip/hip_runtime.h>

#define N_NODES 512
#define C_CH    128
#define S_SPEC  10
#define KT      50
#define NT      11

typedef _Float16 h8 __attribute__((ext_vector_type(8)));
typedef float f32x4 __attribute__((ext_vector_type(4)));

// K layout: 50 tiles x 32 slots; tile = 4 octets (one per lane-group g).
// Octet = (offA, offB, j0): slot i computes x[offA]*x[offB]*x[j0+i], j0 in {0,8}.
// Octets 0..171: order-3 (a<=b, run over j>=b; j0=0 octet exists iff b<8)
// 172..195: order-2 (offB=16 -> ones; run over b>=a); 196..197: order-1; 198..199: pad(zero).
// N cols (o-major): nt 0..6 = k3, 7..9 = k2, 10 = k1; col = o (0..15) within tile.
__device__ h8  g_Bf[KT * NT * 64];   // B pre-swizzled to MFMA B-frag order [kt][nt][lane]
__device__ int g_runtab[KT * 4];     // octet descriptors: offA | offB<<5 | j0bit<<10

__device__ __forceinline__ void o_to_iri(int o, int& ir, int& i) {
  if (o >= 9)      { ir = 3; i = o - 9; }
  else if (o >= 4) { ir = 2; i = o - 4; }
  else if (o >= 1) { ir = 1; i = o - 1; }
  else             { ir = 0; i = 0; }
}

__device__ int octet_desc(int Q) {
  if (Q < 172) {                     // order-3
    int q = Q;
    for (int a = 0; a < 16; ++a)
      for (int b = a; b < 16; ++b) {
        int no = (b < 8) ? 2 : 1;
        if (q < no) {
          int jb = (no == 1) ? 1 : q;          // b<8: q0->j0=0,q1->j0=8; b>=8: j0=8
          return a | (b << 5) | (jb << 10);
        }
        q -= no;
      }
  } else if (Q < 196) {              // order-2
    int q = Q - 172;
    for (int a = 0; a < 16; ++a) {
      int no = (a < 8) ? 2 : 1;
      if (q < no) {
        int jb = (no == 1) ? 1 : q;
        return a | (16 << 5) | (jb << 10);
      }
      q -= no;
    }
  } else if (Q < 198) {              // order-1
    return 16 | (16 << 5) | ((Q - 196) << 10);
  }
  return 17 | (17 << 5);             // pad (zero column)
}

__global__ void build_runtab() {
  int Q = threadIdx.x;
  if (Q < KT * 4) g_runtab[Q] = octet_desc(Q);
}

__global__ void build_B(const float* __restrict__ u1_0, const float* __restrict__ u1_1,
                        const float* __restrict__ u1_2, const float* __restrict__ u1_3,
                        const float* __restrict__ u2_0, const float* __restrict__ u2_1,
                        const float* __restrict__ u2_2, const float* __restrict__ u2_3,
                        const float* __restrict__ u3_0, const float* __restrict__ u3_1,
                        const float* __restrict__ u3_2, const float* __restrict__ u3_3) {
  const int bid = blockIdx.x;
  int kt, nt;
  if (bid < 301)      { kt = bid / 7; nt = bid % 7; }
  else if (bid < 319) { int e = bid - 301; kt = 43 + e / 3; nt = 7 + e % 3; }
  else                { kt = 49; nt = 10; }

  const int l = threadIdx.x;
  const int o = l & 15;
  int ir, ii; o_to_iri(o, ir, ii);
  const int dis[4] = {1, 3, 5, 7};
  const int di = dis[ir];
  const float* u1s[4] = {u1_0, u1_1, u1_2, u1_3};
  const float* u2s[4] = {u2_0, u2_1, u2_2, u2_3};
  const float* u3s[4] = {u3_0, u3_1, u3_2, u3_3};

  const int rt = g_runtab[kt * 4 + (l >> 4)];
  const int oA = rt & 31, oB = (rt >> 5) & 31, j0 = ((rt >> 10) & 1) * 8;

  h8 v;
#pragma unroll
  for (int i = 0; i < 8; ++i) {
    const int j = j0 + i;
    float val = 0.f;
    if (oA < 16 && oB < 16) {              // order-3, canonical a<=b<=j
      if (j >= oB) {
        const float* u = u3s[ir];
        int a = oA, b = oB;
        int P[6][3] = {{a,b,j},{a,j,b},{b,a,j},{b,j,a},{j,a,b},{j,b,a}};
        for (int p = 0; p < 6; ++p) {
          bool dup = false;
          for (int r = 0; r < p; ++r)
            if (P[r][0] == P[p][0] && P[r][1] == P[p][1] && P[r][2] == P[p][2]) { dup = true; break; }
          if (!dup)
            val += u[(((P[p][0] * 16 + P[p][1]) * 16 + P[p][2]) * 7 + nt) * di + ii];
        }
      }
    } else if (oA < 16 && oB == 16) {      // order-2, pair (oA <= j)
      if (j >= oA) {
        const int k2 = nt - 7;
        const float* u = u2s[ir];
        val = u[((oA * 16 + j) * 3 + k2) * di + ii];
        if (j != oA) val += u[((j * 16 + oA) * 3 + k2) * di + ii];
      }
    } else if (oA == 16) {                 // order-1
      val = u1s[ir][j * di + ii];
    }
    v[i] = (_Float16)val;
  }
  g_Bf[((size_t)kt * NT + nt) * 64 + l] = v;
}

// ---------------- main MFMA kernel: 2 nodes per wave M-tile, B prefetch ----------------

#define MFMA16(A, B, C) __builtin_amdgcn_mfma_f32_16x16x32_f16(A, B, C, 0, 0, 0)

#define LOADB(KTv, B) {                                                        \
  const h8* bp_ = &g_Bf[((size_t)(KTv) * NT) * 64 + l];                        \
  if ((KTv) < 43) {                                                            \
    B[0] = bp_[0];     B[1] = bp_[64];    B[2] = bp_[128];  B[3] = bp_[192];   \
    B[4] = bp_[256];   B[5] = bp_[320];   B[6] = bp_[384];                     \
  } else if ((KTv) < 49) {                                                     \
    B[0] = bp_[7 * 64]; B[1] = bp_[8 * 64]; B[2] = bp_[9 * 64];                \
  } else {                                                                     \
    B[0] = bp_[10 * 64];                                                       \
  }                                                                            \
}

#define STEP(KTv, B) {                                                         \
  const int rt_ = rt4[(KTv) * 4 + g];                                          \
  const int oA_ = rt_ & 31, oB_ = (rt_ >> 5) & 31, jb_ = (rt_ >> 10) & 1;      \
  const float xa0_ = xr0[oA_], xb0_ = xr0[oB_];                                \
  const float xa1_ = xr1[oA_], xb1_ = xr1[oB_];                                \
  const float4 lo0_ = jb_ ? x0c : x0a, hi0_ = jb_ ? x0d : x0b;                 \
  const float4 lo1_ = jb_ ? x1c : x1a, hi1_ = jb_ ? x1d : x1b;                 \
  const float m0_ = xa0_ * xb0_, m1_ = xa1_ * xb1_;                            \
  h8 af0_, af1_;                                                               \
  af0_[0] = (_Float16)(m0_ * lo0_.x); af0_[1] = (_Float16)(m0_ * lo0_.y);      \
  af0_[2] = (_Float16)(m0_ * lo0_.z); af0_[3] = (_Float16)(m0_ * lo0_.w);      \
  af0_[4] = (_Float16)(m0_ * hi0_.x); af0_[5] = (_Float16)(m0_ * hi0_.y);      \
  af0_[6] = (_Float16)(m0_ * hi0_.z); af0_[7] = (_Float16)(m0_ * hi0_.w);      \
  af1_[0] = (_Float16)(m1_ * lo1_.x); af1_[1] = (_Float16)(m1_ * lo1_.y);      \
  af1_[2] = (_Float16)(m1_ * lo1_.z); af1_[3] = (_Float16)(m1_ * lo1_.w);      \
  af1_[4] = (_Float16)(m1_ * hi1_.x); af1_[5] = (_Float16)(m1_ * hi1_.y);      \
  af1_[6] = (_Float16)(m1_ * hi1_.z); af1_[7] = (_Float16)(m1_ * hi1_.w);      \
  if ((KTv) < 43) {                                                            \
    acc[0][0] = MFMA16(af0_, B[0], acc[0][0]); acc[1][0] = MFMA16(af1_, B[0], acc[1][0]); \
    acc[0][1] = MFMA16(af0_, B[1], acc[0][1]); acc[1][1] = MFMA16(af1_, B[1], acc[1][1]); \
    acc[0][2] = MFMA16(af0_, B[2], acc[0][2]); acc[1][2] = MFMA16(af1_, B[2], acc[1][2]); \
    acc[0][3] = MFMA16(af0_, B[3], acc[0][3]); acc[1][3] = MFMA16(af1_, B[3], acc[1][3]); \
    acc[0][4] = MFMA16(af0_, B[4], acc[0][4]); acc[1][4] = MFMA16(af1_, B[4], acc[1][4]); \
    acc[0][5] = MFMA16(af0_, B[5], acc[0][5]); acc[1][5] = MFMA16(af1_, B[5], acc[1][5]); \
    acc[0][6] = MFMA16(af0_, B[6], acc[0][6]); acc[1][6] = MFMA16(af1_, B[6], acc[1][6]); \
  } else if ((KTv) < 49) {                                                     \
    acc[0][7] = MFMA16(af0_, B[0], acc[0][7]); acc[1][7] = MFMA16(af1_, B[0], acc[1][7]); \
    acc[0][8] = MFMA16(af0_, B[1], acc[0][8]); acc[1][8] = MFMA16(af1_, B[1], acc[1][8]); \
    acc[0][9] = MFMA16(af0_, B[2], acc[0][9]); acc[1][9] = MFMA16(af1_, B[2], acc[1][9]); \
  } else {                                                                     \
    acc[0][10] = MFMA16(af0_, B[0], acc[0][10]); acc[1][10] = MFMA16(af1_, B[0], acc[1][10]); \
  }                                                                            \
}

__global__ __launch_bounds__(512) void eqp_mm(
    const float* __restrict__ x, const int* __restrict__ specie,
    const float* __restrict__ w1, const float* __restrict__ w2,
    const float* __restrict__ w3, float* __restrict__ ws, int nsp) {
  __shared__ float xc[2 * 128 * 19];   // [node][c][19]: cols 0..15 x, 16 = 1, 17 = 0
  __shared__ int rt4[KT * 4];

  const int t = threadIdx.x;
  const int l = t & 63;
  const int w = t >> 6;
  const int g = l >> 4;
  const int n0 = blockIdx.x * 2;
  const int ks = blockIdx.y;

  {  // stage x into LDS (node, half split over t>>7)
    const int c = t & 127, h = t >> 7;
    const int node = h >> 1, half = h & 1;
    const float* xp = x + ((size_t)(n0 + node) * C_CH + c) * 16 + half * 8;
    const float4 v0 = *(const float4*)xp, v1 = *(const float4*)(xp + 4);
    float* row = &xc[(node * 128 + c) * 19];
    row[half * 8 + 0] = v0.x; row[half * 8 + 1] = v0.y;
    row[half * 8 + 2] = v0.z; row[half * 8 + 3] = v0.w;
    row[half * 8 + 4] = v1.x; row[half * 8 + 5] = v1.y;
    row[half * 8 + 6] = v1.z; row[half * 8 + 7] = v1.w;
    if (half == 0) { row[16] = 1.f; row[17] = 0.f; }
    if (t < KT * 4) rt4[t] = g_runtab[t];
  }
  __syncthreads();

  const int ch = w * 16 + (l & 15);
  const int s0 = specie[n0], s1 = specie[n0 + 1];

  // x in registers (j-octets selected by cndmask on j0 bit)
  float4 x0a, x0b, x0c, x0d, x1a, x1b, x1c, x1d;
  {
    const float4* p0 = (const float4*)(x + ((size_t)n0 * C_CH + ch) * 16);
    x0a = p0[0]; x0b = p0[1]; x0c = p0[2]; x0d = p0[3];
    const float4* p1 = (const float4*)(x + ((size_t)(n0 + 1) * C_CH + ch) * 16);
    x1a = p1[0]; x1b = p1[1]; x1c = p1[2]; x1d = p1[3];
  }
  const float* xr0 = &xc[(0 * 128 + ch) * 19];
  const float* xr1 = &xc[(128 + ch) * 19];

  f32x4 acc[2][NT];
#pragma unroll
  for (int p = 0; p < 2; ++p)
#pragma unroll
    for (int i = 0; i < NT; ++i) acc[p][i] = (f32x4){0.f, 0.f, 0.f, 0.f};

  const int kt0 = (nsp == 2 && ks == 1) ? 22 : 0;
  const int kt1 = (nsp == 2 && ks == 0) ? 22 : KT;

  h8 ba[7], bb[7];
  LOADB(kt0, ba);
  int kt = kt0;
  while (kt < kt1) {
    if (kt + 1 < kt1) LOADB(kt + 1, bb);
    STEP(kt, ba);
    ++kt;
    if (kt >= kt1) break;
    if (kt + 1 < kt1) LOADB(kt + 1, ba);
    STEP(kt, bb);
    ++kt;
  }

  // ---- fold species weights from C-fragment, write partials ----
  {
    const int o = l & 15;
    int ir, ii; o_to_iri(o, ir, ii); (void)ii;
    const int cb = w * 16 + g * 4;   // 4 consecutive channel rows (C-frag regs)
#pragma unroll
    for (int p = 0; p < 2; ++p) {
      const int sp = p ? s1 : s0;
      float tot[4] = {0.f, 0.f, 0.f, 0.f};
#pragma unroll
      for (int k = 0; k < 7; ++k) {
        const float4 wv = *(const float4*)(w3 + ((size_t)(ir * S_SPEC + sp) * 7 + k) * C_CH + cb);
        tot[0] = fmaf(wv.x, acc[p][k][0], tot[0]);
        tot[1] = fmaf(wv.y, acc[p][k][1], tot[1]);
        tot[2] = fmaf(wv.z, acc[p][k][2], tot[2]);
        tot[3] = fmaf(wv.w, acc[p][k][3], tot[3]);
      }
#pragma unroll
      for (int k = 0; k < 3; ++k) {
        const float4 wv = *(const float4*)(w2 + ((size_t)(ir * S_SPEC + sp) * 3 + k) * C_CH + cb);
        tot[0] = fmaf(wv.x, acc[p][7 + k][0], tot[0]);
        tot[1] = fmaf(wv.y, acc[p][7 + k][1], tot[1]);
        tot[2] = fmaf(wv.z, acc[p][7 + k][2], tot[2]);
        tot[3] = fmaf(wv.w, acc[p][7 + k][3], tot[3]);
      }
      {
        const float4 wv = *(const float4*)(w1 + (size_t)(ir * S_SPEC + sp) * C_CH + cb);
        tot[0] = fmaf(wv.x, acc[p][10][0], tot[0]);
        tot[1] = fmaf(wv.y, acc[p][10][1], tot[1]);
        tot[2] = fmaf(wv.z, acc[p][10][2], tot[2]);
        tot[3] = fmaf(wv.w, acc[p][10][3], tot[3]);
      }
      float4 st = {tot[0], tot[1], tot[2], tot[3]};
      *(float4*)(ws + (((size_t)ks * N_NODES + (n0 + p)) * 16 + o) * C_CH + cb) = st;
    }
  }
}

// ---------------- epilogue: sum partials + wlin channel mix ----------------

template <int HH>
__device__ __forceinline__ void lin_half(const float* __restrict__ redS,
                                         const float* __restrict__ wlin,
                                         float* __restrict__ out, int n, int f) {
  constexpr int irOfA[16] = {0,1,1,1,2,2,2,2,2,3,3,3,3,3,3,3};
  constexpr int iOfA[16]  = {0,0,1,2,0,1,2,3,4,0,1,2,3,4,5,6};
  constexpr int diA[4]  = {1, 3, 5, 7};
  constexpr int ooff[4] = {0, 128, 512, 1152};
  float res[8];
#pragma unroll
  for (int oo = 0; oo < 8; ++oo) res[oo] = 0.f;
#pragma unroll 2
  for (int cc = 0; cc < 128; ++cc) {
    float wv[4];
#pragma unroll
    for (int ir = 0; ir < 4; ++ir) wv[ir] = 0.f;
#pragma unroll
    for (int ir = 0; ir < 4; ++ir) {
      bool need = false;
#pragma unroll
      for (int oo = 0; oo < 8; ++oo) need = need || (irOfA[HH * 8 + oo] == ir);
      if (need) wv[ir] = wlin[((size_t)ir * C_CH + cc) * C_CH + f];
    }
#pragma unroll
    for (int oo = 0; oo < 8; ++oo)
      res[oo] = fmaf(redS[(HH * 8 + oo) * 128 + cc], wv[irOfA[HH * 8 + oo]], res[oo]);
  }
  const float inv = 0.08838834764831845f;  // 1/sqrt(128)
  size_t base = (size_t)n * 2048;
#pragma unroll
  for (int oo = 0; oo < 8; ++oo) {
    int o = HH * 8 + oo;
    out[base + ooff[irOfA[o]] + (size_t)f * diA[irOfA[o]] + iOfA[o]] = res[oo] * inv;
  }
}

__global__ __launch_bounds__(256) void eqp_lin(
    const float* __restrict__ ws, const float* __restrict__ wlin,
    float* __restrict__ out, int nsp) {
  __shared__ float redS[2048];  // [o][c]
  const int t = threadIdx.x;
  const int n = blockIdx.x;
  {
    const float4* p0 = (const float4*)(ws + (size_t)n * 2048);
    float4 a = p0[t], b = p0[t + 256];
    if (nsp == 2) {
      const float4* p1 = (const float4*)(ws + ((size_t)N_NODES + n) * 2048);
      float4 a1 = p1[t], b1 = p1[t + 256];
      a.x += a1.x; a.y += a1.y; a.z += a1.z; a.w += a1.w;
      b.x += b1.x; b.y += b1.y; b.z += b1.z; b.w += b1.w;
    }
    ((float4*)redS)[t] = a;
    ((float4*)redS)[t + 256] = b;
  }
  __syncthreads();
  const int f = t & 127;
  if ((t >> 7) == 0) lin_half<0>(redS, wlin, out, n, f);
  else               lin_half<1>(redS, wlin, out, n, f);
}

// ---------------- launch ----------------

extern "C" void kernel_launch(void* const* d_in, const int* in_sizes, int n_in,
                              void* d_out, int out_size, void* d_ws, size_t ws_size,
                              hipStream_t stream) {
  const float* x      = (const float*)d_in[0];
  const int*   specie = (const int*)d_in[1];

  const float *u1s[4], *u2s[4], *u3s[4];
  if (in_sizes[3] == 768) {  // interleaved dict order: u1_0,u2_0,u3_0,u1_1,...
    for (int i = 0; i < 4; ++i) {
      u1s[i] = (const float*)d_in[2 + 3 * i];
      u2s[i] = (const float*)d_in[3 + 3 * i];
      u3s[i] = (const float*)d_in[4 + 3 * i];
    }
  } else {                   // grouped order: u1_0..u1_3,u2_0..u2_3,u3_0..u3_3
    for (int i = 0; i < 4; ++i) {
      u1s[i] = (const float*)d_in[2 + i];
      u2s[i] = (const float*)d_in[6 + i];
      u3s[i] = (const float*)d_in[10 + i];
    }
  }
  const float* w1   = (const float*)d_in[14];
  const float* w2   = (const float*)d_in[15];
  const float* w3   = (const float*)d_in[16];
  const float* wlin = (const float*)d_in[17];
  float* out = (float*)d_out;
  float* ws  = (float*)d_ws;

  const size_t need2 = 2ull * N_NODES * 2048 * sizeof(float);
  const int nsp = (ws_size >= need2) ? 2 : 1;

  build_runtab<<<1, 256, 0, stream>>>();
  build_B<<<320, 64, 0, stream>>>(
      u1s[0], u1s[1], u1s[2], u1s[3],
      u2s[0], u2s[1], u2s[2], u2s[3],
      u3s[0], u3s[1], u3s[2], u3s[3]);
  eqp_mm<<<dim3(N_NODES / 2, nsp), 512, 0, stream>>>(x, specie, w1, w2, w3, ws, nsp);
  eqp_lin<<<N_NODES, 256, 0, stream>>>(ws, wlin, out, nsp);
}

// Round 6
// 74.901 us; speedup vs baseline: 2.1177x; 2.1177x over previous
//
#include <hip/hip_runtime.h>

#define N_NODES 512
#define C_CH    128
#define S_SPEC  10
#define KT      50
#define NT      11

typedef _Float16 h8 __attribute__((ext_vector_type(8)));
typedef float f32x4 __attribute__((ext_vector_type(4)));

// K layout: 50 tiles x 32 slots; tile = 4 octets (one per lane-group g).
// Octet = (offA, offB, j0): slot i computes x[offA]*x[offB]*x[j0+i], j0 in {0,8}.
// N cols (o-major): nt 0..6 = k3, 7..9 = k2, 10 = k1; col = o (0..15).
__device__ h8 g_Bf[KT * NT * 64];   // B pre-swizzled to MFMA B-frag order [kt][nt][lane]

__device__ __forceinline__ int fc_of(int kt)  { return kt < 43 ? 7 : (kt < 49 ? 3 : 1); }
__device__ __forceinline__ int ntb_of(int kt) { return kt < 43 ? 0 : (kt < 49 ? 7 : 10); }

__device__ __forceinline__ void o_to_iri(int o, int& ir, int& i) {
  if (o >= 9)      { ir = 3; i = o - 9; }
  else if (o >= 4) { ir = 2; i = o - 4; }
  else if (o >= 1) { ir = 1; i = o - 1; }
  else             { ir = 0; i = 0; }
}

__device__ int octet_desc(int Q) {
  if (Q < 172) {                     // order-3
    int q = Q;
    for (int a = 0; a < 16; ++a)
      for (int b = a; b < 16; ++b) {
        int no = (b < 8) ? 2 : 1;
        if (q < no) {
          int jb = (no == 1) ? 1 : q;          // b<8: q0->j0=0,q1->j0=8; b>=8: j0=8
          return a | (b << 5) | (jb << 10);
        }
        q -= no;
      }
  } else if (Q < 196) {              // order-2
    int q = Q - 172;
    for (int a = 0; a < 16; ++a) {
      int no = (a < 8) ? 2 : 1;
      if (q < no) {
        int jb = (no == 1) ? 1 : q;
        return a | (16 << 5) | (jb << 10);
      }
      q -= no;
    }
  } else if (Q < 198) {              // order-1
    return 16 | (16 << 5) | ((Q - 196) << 10);
  }
  return 17 | (17 << 5);             // pad (zero column)
}

__global__ void build_B(const float* __restrict__ u1_0, const float* __restrict__ u1_1,
                        const float* __restrict__ u1_2, const float* __restrict__ u1_3,
                        const float* __restrict__ u2_0, const float* __restrict__ u2_1,
                        const float* __restrict__ u2_2, const float* __restrict__ u2_3,
                        const float* __restrict__ u3_0, const float* __restrict__ u3_1,
                        const float* __restrict__ u3_2, const float* __restrict__ u3_3) {
  const int bid = blockIdx.x;
  int kt, nt;
  if (bid < 301)      { kt = bid / 7; nt = bid % 7; }
  else if (bid < 319) { int e = bid - 301; kt = 43 + e / 3; nt = 7 + e % 3; }
  else                { kt = 49; nt = 10; }

  const int l = threadIdx.x;
  const int o = l & 15;
  int ir, ii; o_to_iri(o, ir, ii);
  const int dis[4] = {1, 3, 5, 7};
  const int di = dis[ir];
  const float* u1s[4] = {u1_0, u1_1, u1_2, u1_3};
  const float* u2s[4] = {u2_0, u2_1, u2_2, u2_3};
  const float* u3s[4] = {u3_0, u3_1, u3_2, u3_3};

  const int rt = octet_desc(kt * 4 + (l >> 4));
  const int oA = rt & 31, oB = (rt >> 5) & 31, j0 = ((rt >> 10) & 1) * 8;

  h8 v;
#pragma unroll
  for (int i = 0; i < 8; ++i) {
    const int j = j0 + i;
    float val = 0.f;
    if (oA < 16 && oB < 16) {              // order-3, canonical a<=b<=j
      if (j >= oB) {
        const float* u = u3s[ir];
        int a = oA, b = oB;
        int P[6][3] = {{a,b,j},{a,j,b},{b,a,j},{b,j,a},{j,a,b},{j,b,a}};
        for (int p = 0; p < 6; ++p) {
          bool dup = false;
          for (int r = 0; r < p; ++r)
            if (P[r][0] == P[p][0] && P[r][1] == P[p][1] && P[r][2] == P[p][2]) { dup = true; break; }
          if (!dup)
            val += u[(((P[p][0] * 16 + P[p][1]) * 16 + P[p][2]) * 7 + nt) * di + ii];
        }
      }
    } else if (oA < 16 && oB == 16) {      // order-2 (oA <= j)
      if (j >= oA) {
        const int k2 = nt - 7;
        const float* u = u2s[ir];
        val = u[((oA * 16 + j) * 3 + k2) * di + ii];
        if (j != oA) val += u[((j * 16 + oA) * 3 + k2) * di + ii];
      }
    } else if (oA == 16) {                 // order-1
      val = u1s[ir][j * di + ii];
    }
    v[i] = (_Float16)val;
  }
  g_Bf[((size_t)kt * NT + nt) * 64 + l] = v;
}

// ---------------- fused main kernel: 2 nodes/block, chunked LDS B, in-kernel wlin ----

#define MFMA16(A, B, C) __builtin_amdgcn_mfma_f32_16x16x32_f16(A, B, C, 0, 0, 0)

template <int HH>
__device__ __forceinline__ void lin_half132(const float* __restrict__ rp,
                                            const float* __restrict__ wlin,
                                            float* __restrict__ out, int n, int f) {
  constexpr int irOfA[16] = {0,1,1,1,2,2,2,2,2,3,3,3,3,3,3,3};
  constexpr int iOfA[16]  = {0,0,1,2,0,1,2,3,4,0,1,2,3,4,5,6};
  constexpr int diA[4]  = {1, 3, 5, 7};
  constexpr int ooff[4] = {0, 128, 512, 1152};
  float res[8];
#pragma unroll
  for (int oo = 0; oo < 8; ++oo) res[oo] = 0.f;
#pragma unroll 2
  for (int cc = 0; cc < 128; ++cc) {
    float wv[4];
#pragma unroll
    for (int ir = 0; ir < 4; ++ir) wv[ir] = 0.f;
#pragma unroll
    for (int ir = 0; ir < 4; ++ir) {
      bool need = false;
#pragma unroll
      for (int oo = 0; oo < 8; ++oo) need = need || (irOfA[HH * 8 + oo] == ir);
      if (need) wv[ir] = wlin[((size_t)ir * C_CH + cc) * C_CH + f];
    }
#pragma unroll
    for (int oo = 0; oo < 8; ++oo)
      res[oo] = fmaf(rp[(HH * 8 + oo) * 132 + cc], wv[irOfA[HH * 8 + oo]], res[oo]);
  }
  const float inv = 0.08838834764831845f;  // 1/sqrt(128)
  size_t base = (size_t)n * 2048;
#pragma unroll
  for (int oo = 0; oo < 8; ++oo) {
    int o = HH * 8 + oo;
    out[base + ooff[irOfA[o]] + (size_t)f * diA[irOfA[o]] + iOfA[o]] = res[oo] * inv;
  }
}

__global__ __launch_bounds__(512, 1) void eqp_mm(
    const float* __restrict__ x, const int* __restrict__ specie,
    const float* __restrict__ w1, const float* __restrict__ w2,
    const float* __restrict__ w3, const float* __restrict__ wlin,
    float* __restrict__ out) {
  __shared__ __align__(16) char bsraw[35 * 1024];   // B chunk buffer; aliased by redS later
  __shared__ float xT[2][128][18];                  // cols 0..15 x, 16 = 1, 17 = 0
  __shared__ int rtab[KT * 4];

  const int t = threadIdx.x;
  const int l = t & 63;
  const int w = t >> 6;
  const int g = l >> 4;
  const int n0 = blockIdx.x * 2;

  {  // stage xT + rtab
    const int p = t >> 8, c = (t >> 1) & 127, half = t & 1;
    const float* xp = x + ((size_t)(n0 + p) * C_CH + c) * 16 + half * 8;
    const float4 v0 = *(const float4*)xp, v1 = *(const float4*)(xp + 4);
    float* row = &xT[p][c][half * 8];
    row[0] = v0.x; row[1] = v0.y; row[2] = v0.z; row[3] = v0.w;
    row[4] = v1.x; row[5] = v1.y; row[6] = v1.z; row[7] = v1.w;
    if (half == 1) { xT[p][c][16] = 1.f; xT[p][c][17] = 0.f; }
    if (t < KT * 4) rtab[t] = octet_desc(t);
  }

  const int ch = w * 16 + (l & 15);
  const int s0 = specie[n0], s1 = specie[n0 + 1];

  // x rows in registers for the j-octet (selected by cndmask on j0 bit)
  float4 x0a, x0b, x0c, x0d, x1a, x1b, x1c, x1d;
  {
    const float4* p0 = (const float4*)(x + ((size_t)n0 * C_CH + ch) * 16);
    x0a = p0[0]; x0b = p0[1]; x0c = p0[2]; x0d = p0[3];
    const float4* p1 = (const float4*)(x + ((size_t)(n0 + 1) * C_CH + ch) * 16);
    x1a = p1[0]; x1b = p1[1]; x1c = p1[2]; x1d = p1[3];
  }

  f32x4 acc[2][NT];
#pragma unroll
  for (int p = 0; p < 2; ++p)
#pragma unroll
    for (int i = 0; i < NT; ++i) acc[p][i] = (f32x4){0.f, 0.f, 0.f, 0.f};

#define BRD(i) (*(const h8*)&bsraw[(size_t)(fb2 + (i)) * 1024 + (size_t)l * 16])

#pragma unroll 1
  for (int ck = 0; ck < 10; ++ck) {
    const int cs = ck * 5;
    // frag count this chunk
    int nf = 0;
#pragma unroll
    for (int tt = 0; tt < 5; ++tt) nf += fc_of(cs + tt);

    // ---- issue this chunk's global B loads (before barrier: hides latency) ----
    h8 tv[5]; int dst[5];
#pragma unroll
    for (int slot = 0; slot < 5; ++slot) {
      const int fi = slot * 8 + w;
      const bool ok = fi < nf;
      int kt = cs, rem = fi;
      if (ok) { while (rem >= fc_of(kt)) { rem -= fc_of(kt); ++kt; } }
      dst[slot] = ok ? fi : -1;
      if (ok) tv[slot] = g_Bf[((size_t)kt * NT + (ntb_of(kt) + rem)) * 64 + l];
    }
    __syncthreads();   // prev chunk consumed (and, for ck=0, xT/rtab visible)
#pragma unroll
    for (int slot = 0; slot < 5; ++slot)
      if (dst[slot] >= 0) *(h8*)&bsraw[(size_t)dst[slot] * 1024 + (size_t)l * 16] = tv[slot];
    __syncthreads();

    // ---- consume 5 tiles ----
    int fb2 = 0;
#pragma unroll
    for (int tt = 0; tt < 5; ++tt) {
      const int kt = cs + tt;
      const int rt_ = rtab[kt * 4 + g];
      const int oA_ = rt_ & 31, oB_ = (rt_ >> 5) & 31, jb_ = (rt_ >> 10) & 1;
      const float xab0 = xT[0][ch][oA_] * xT[0][ch][oB_];
      const float xab1 = xT[1][ch][oA_] * xT[1][ch][oB_];
      const float4 lo0 = jb_ ? x0c : x0a, hi0 = jb_ ? x0d : x0b;
      const float4 lo1 = jb_ ? x1c : x1a, hi1 = jb_ ? x1d : x1b;
      h8 af0, af1;
      af0[0] = (_Float16)(xab0 * lo0.x); af0[1] = (_Float16)(xab0 * lo0.y);
      af0[2] = (_Float16)(xab0 * lo0.z); af0[3] = (_Float16)(xab0 * lo0.w);
      af0[4] = (_Float16)(xab0 * hi0.x); af0[5] = (_Float16)(xab0 * hi0.y);
      af0[6] = (_Float16)(xab0 * hi0.z); af0[7] = (_Float16)(xab0 * hi0.w);
      af1[0] = (_Float16)(xab1 * lo1.x); af1[1] = (_Float16)(xab1 * lo1.y);
      af1[2] = (_Float16)(xab1 * lo1.z); af1[3] = (_Float16)(xab1 * lo1.w);
      af1[4] = (_Float16)(xab1 * hi1.x); af1[5] = (_Float16)(xab1 * hi1.y);
      af1[6] = (_Float16)(xab1 * hi1.z); af1[7] = (_Float16)(xab1 * hi1.w);
      if (kt < 43) {
        h8 b0 = BRD(0), b1 = BRD(1), b2 = BRD(2), b3 = BRD(3), b4 = BRD(4), b5 = BRD(5), b6 = BRD(6);
        acc[0][0] = MFMA16(af0, b0, acc[0][0]); acc[1][0] = MFMA16(af1, b0, acc[1][0]);
        acc[0][1] = MFMA16(af0, b1, acc[0][1]); acc[1][1] = MFMA16(af1, b1, acc[1][1]);
        acc[0][2] = MFMA16(af0, b2, acc[0][2]); acc[1][2] = MFMA16(af1, b2, acc[1][2]);
        acc[0][3] = MFMA16(af0, b3, acc[0][3]); acc[1][3] = MFMA16(af1, b3, acc[1][3]);
        acc[0][4] = MFMA16(af0, b4, acc[0][4]); acc[1][4] = MFMA16(af1, b4, acc[1][4]);
        acc[0][5] = MFMA16(af0, b5, acc[0][5]); acc[1][5] = MFMA16(af1, b5, acc[1][5]);
        acc[0][6] = MFMA16(af0, b6, acc[0][6]); acc[1][6] = MFMA16(af1, b6, acc[1][6]);
        fb2 += 7;
      } else if (kt < 49) {
        h8 b0 = BRD(0), b1 = BRD(1), b2 = BRD(2);
        acc[0][7] = MFMA16(af0, b0, acc[0][7]); acc[1][7] = MFMA16(af1, b0, acc[1][7]);
        acc[0][8] = MFMA16(af0, b1, acc[0][8]); acc[1][8] = MFMA16(af1, b1, acc[1][8]);
        acc[0][9] = MFMA16(af0, b2, acc[0][9]); acc[1][9] = MFMA16(af1, b2, acc[1][9]);
        fb2 += 3;
      } else {
        h8 b0 = BRD(0);
        acc[0][10] = MFMA16(af0, b0, acc[0][10]); acc[1][10] = MFMA16(af1, b0, acc[1][10]);
        fb2 += 1;
      }
    }
  }

  // ---- fold species weights -> redS (aliases bsraw), then in-kernel wlin ----
  __syncthreads();   // all B reads done before overwriting bsraw
  float* redS = (float*)bsraw;   // [p][o][132]
  {
    const int o = l & 15;
    int ir, ii; o_to_iri(o, ir, ii); (void)ii;
    const int cb = w * 16 + g * 4;
#pragma unroll
    for (int p = 0; p < 2; ++p) {
      const int sp = p ? s1 : s0;
      float tot[4] = {0.f, 0.f, 0.f, 0.f};
#pragma unroll
      for (int k = 0; k < 7; ++k) {
        const float4 wv = *(const float4*)(w3 + ((size_t)(ir * S_SPEC + sp) * 7 + k) * C_CH + cb);
        tot[0] = fmaf(wv.x, acc[p][k][0], tot[0]);
        tot[1] = fmaf(wv.y, acc[p][k][1], tot[1]);
        tot[2] = fmaf(wv.z, acc[p][k][2], tot[2]);
        tot[3] = fmaf(wv.w, acc[p][k][3], tot[3]);
      }
#pragma unroll
      for (int k = 0; k < 3; ++k) {
        const float4 wv = *(const float4*)(w2 + ((size_t)(ir * S_SPEC + sp) * 3 + k) * C_CH + cb);
        tot[0] = fmaf(wv.x, acc[p][7 + k][0], tot[0]);
        tot[1] = fmaf(wv.y, acc[p][7 + k][1], tot[1]);
        tot[2] = fmaf(wv.z, acc[p][7 + k][2], tot[2]);
        tot[3] = fmaf(wv.w, acc[p][7 + k][3], tot[3]);
      }
      {
        const float4 wv = *(const float4*)(w1 + (size_t)(ir * S_SPEC + sp) * C_CH + cb);
        tot[0] = fmaf(wv.x, acc[p][10][0], tot[0]);
        tot[1] = fmaf(wv.y, acc[p][10][1], tot[1]);
        tot[2] = fmaf(wv.z, acc[p][10][2], tot[2]);
        tot[3] = fmaf(wv.w, acc[p][10][3], tot[3]);
      }
      float4 st = {tot[0], tot[1], tot[2], tot[3]};
      *(float4*)&redS[(p * 16 + o) * 132 + cb] = st;
    }
  }
  __syncthreads();

  {
    const int p2 = t >> 8;
    const int tid = t & 255;
    const int f = tid & 127;
    const float* rp = redS + p2 * (16 * 132);
    if ((tid >> 7) == 0) lin_half132<0>(rp, wlin, out, n0 + p2, f);
    else                 lin_half132<1>(rp, wlin, out, n0 + p2, f);
  }
}

// ---------------- launch ----------------

extern "C" void kernel_launch(void* const* d_in, const int* in_sizes, int n_in,
                              void* d_out, int out_size, void* d_ws, size_t ws_size,
                              hipStream_t stream) {
  const float* x      = (const float*)d_in[0];
  const int*   specie = (const int*)d_in[1];

  const float *u1s[4], *u2s[4], *u3s[4];
  if (in_sizes[3] == 768) {  // interleaved dict order: u1_0,u2_0,u3_0,u1_1,...
    for (int i = 0; i < 4; ++i) {
      u1s[i] = (const float*)d_in[2 + 3 * i];
      u2s[i] = (const float*)d_in[3 + 3 * i];
      u3s[i] = (const float*)d_in[4 + 3 * i];
    }
  } else {                   // grouped order: u1_0..u1_3,u2_0..u2_3,u3_0..u3_3
    for (int i = 0; i < 4; ++i) {
      u1s[i] = (const float*)d_in[2 + i];
      u2s[i] = (const float*)d_in[6 + i];
      u3s[i] = (const float*)d_in[10 + i];
    }
  }
  const float* w1   = (const float*)d_in[14];
  const float* w2   = (const float*)d_in[15];
  const float* w3   = (const float*)d_in[16];
  const float* wlin = (const float*)d_in[17];
  float* out = (float*)d_out;
  (void)d_ws; (void)ws_size; (void)out_size; (void)n_in;

  build_B<<<320, 64, 0, stream>>>(
      u1s[0], u1s[1], u1s[2], u1s[3],
      u2s[0], u2s[1], u2s[2], u2s[3],
      u3s[0], u3s[1], u3s[2], u3s[3]);
  eqp_mm<<<N_NODES / 2, 512, 0, stream>>>(x, specie, w1, w2, w3, wlin, out);
}